// Round 2
// baseline (91.100 us; speedup 1.0000x reference)
//
#include <hip/hip_runtime.h>
#include <hip/hip_bf16.h>

// InfoNCE loss, B=8192, D=128, T=0.1.
// sim = normalize(E) @ normalize(E)^T / T ; per-row masked exp-sums; scalar loss.
//
// ws layout:
//   [0        , 32KB) : pos_sum  f32[8192]   (zeroed each call)
//   [32KB     , 64KB) : all_sum  f32[8192]   (zeroed each call)
//   [64KB     , 96KB) : lab32    i32[8192]   (fully written by prep)
//   [96KB     , +2MB) : Ebf      bf16[8192*128] (fully written by prep)

#define B_ROWS 8192
#define D_DIM 128
// log2(e)/0.1
#define K_SCALE 14.426950408889634f

typedef __attribute__((ext_vector_type(8))) short bf16x8;
typedef __attribute__((ext_vector_type(4))) float f32x4;
typedef __attribute__((ext_vector_type(4))) unsigned int u32x4;

static __device__ __forceinline__ unsigned short bf16_bits(float x) {
  __hip_bfloat16 h = __float2bfloat16(x);
  unsigned short u;
  __builtin_memcpy(&u, &h, 2);
  return u;
}

// Normalize rows (fp32 math), emit bf16 matrix + int32 labels.
// 256 threads = 4 waves, one row per wave; grid = B/4.
__global__ __launch_bounds__(256) void prep_kernel(
    const float* __restrict__ E, const long long* __restrict__ labels,
    __hip_bfloat16* __restrict__ Ebf, int* __restrict__ lab32) {
  const int wid = threadIdx.x >> 6, lane = threadIdx.x & 63;
  const int row = blockIdx.x * 4 + wid;
  const float2 v = *(const float2*)(E + row * D_DIM + lane * 2);
  float ss = v.x * v.x + v.y * v.y;
#pragma unroll
  for (int m = 1; m < 64; m <<= 1) ss += __shfl_xor(ss, m);
  const float scale = 1.0f / fmaxf(sqrtf(ss), 1e-12f);
  unsigned int packed = ((unsigned int)bf16_bits(v.y * scale) << 16) |
                        (unsigned int)bf16_bits(v.x * scale);
  ((unsigned int*)Ebf)[row * (D_DIM / 2) + lane] = packed;
  const int gtid = blockIdx.x * 256 + threadIdx.x;
  if (gtid < B_ROWS) lab32[gtid] = (int)labels[gtid];
}

// Fused sim + exp + masked row sums.
// Block: 256 thr = 4 waves; wave w owns rows i0 = bx*64 + w*16.
// Grid: (B/64, 4); blockIdx.y splits the j-range into 4 chunks of 2048.
// LDS: 64x128 bf16 j-tile, XOR-swizzled (byte ^= (row&7)<<4) to kill the
// D=128 row-major 16-way bank conflict on ds_read_b128.
__global__ __launch_bounds__(256) void sim_kernel(
    const __hip_bfloat16* __restrict__ Ebf, const int* __restrict__ lab32,
    float* __restrict__ pos_arr, float* __restrict__ all_arr) {
  __shared__ unsigned char lds[64 * 256];
  __shared__ int labT[64];

  const int t = threadIdx.x;
  const int wid = t >> 6, lane = t & 63;
  const int g = lane >> 4, lr = lane & 15;
  const int i0 = blockIdx.x * 64 + wid * 16;

  // A fragments: lane holds A[lr][k0 + g*8 .. +8] for each 32-wide k slice.
  bf16x8 a_frag[4];
  const int arow = i0 + lr;
#pragma unroll
  for (int kk = 0; kk < 4; ++kk)
    a_frag[kk] = *(const bf16x8*)(Ebf + arow * D_DIM + kk * 32 + g * 8);

  // C/D layout: col = lane&15, row = (lane>>4)*4 + reg  [m89-verified]
  int gi[4], labi[4];
#pragma unroll
  for (int r = 0; r < 4; ++r) {
    gi[r] = i0 + g * 4 + r;
    labi[r] = lab32[gi[r]];
  }

  float pos_acc[4] = {0.f, 0.f, 0.f, 0.f};
  float all_acc[4] = {0.f, 0.f, 0.f, 0.f};
  const int jsplit0 = blockIdx.y * 2048;

  for (int jt = 0; jt < 2048; jt += 64) {
    const int jbase = jsplit0 + jt;
    // Stage 64 rows x 256B, swizzled. Thread t writes 4x16B.
#pragma unroll
    for (int i = 0; i < 4; ++i) {
      const int r = i * 16 + (t >> 4);
      const int cb = (t & 15) * 16;  // byte col within row
      u32x4 v = *(const u32x4*)((const unsigned char*)(Ebf + (jbase + r) * D_DIM) + cb);
      *(u32x4*)(lds + r * 256 + (cb ^ ((r & 7) << 4))) = v;
    }
    if (t < 64) labT[t] = lab32[jbase + t];
    __syncthreads();

#pragma unroll
    for (int jj = 0; jj < 4; ++jj) {
      f32x4 acc = {0.f, 0.f, 0.f, 0.f};
      const int brow = jj * 16 + lr;
#pragma unroll
      for (int kk = 0; kk < 4; ++kk) {
        const int cb = kk * 64 + g * 16;
        bf16x8 b_frag =
            *(const bf16x8*)(lds + brow * 256 + (cb ^ ((brow & 7) << 4)));
        acc = __builtin_amdgcn_mfma_f32_16x16x32_bf16(a_frag[kk], b_frag, acc,
                                                      0, 0, 0);
      }
      const int gj = jbase + jj * 16 + lr;
      const int labj = labT[jj * 16 + lr];
#pragma unroll
      for (int r = 0; r < 4; ++r) {
        const float p = exp2f(acc[r] * K_SCALE);
        const float pv = (gj == gi[r]) ? 0.0f : p;  // exclude diagonal
        all_acc[r] += pv;
        pos_acc[r] += (labj == labi[r]) ? pv : 0.0f;
      }
    }
    __syncthreads();
  }

  // Reduce across the 16 column-lanes of each group (xor<16 stays in-group).
#pragma unroll
  for (int m = 1; m < 16; m <<= 1) {
#pragma unroll
    for (int r = 0; r < 4; ++r) {
      pos_acc[r] += __shfl_xor(pos_acc[r], m);
      all_acc[r] += __shfl_xor(all_acc[r], m);
    }
  }
  if (lr == 0) {
#pragma unroll
    for (int r = 0; r < 4; ++r) {
      atomicAdd(&pos_arr[gi[r]], pos_acc[r]);
      atomicAdd(&all_arr[gi[r]], all_acc[r]);
    }
  }
}

__global__ __launch_bounds__(1024) void finalize_kernel(
    const float* __restrict__ pos_arr, const float* __restrict__ all_arr,
    float* __restrict__ out) {
  float s = 0.f, c = 0.f;
  for (int r = threadIdx.x; r < B_ROWS; r += 1024) {
    const float ps = pos_arr[r];
    if (ps > 0.f) {
      s += logf(all_arr[r]) - logf(ps);
      c += 1.f;
    }
  }
#pragma unroll
  for (int m = 1; m < 64; m <<= 1) {
    s += __shfl_xor(s, m);
    c += __shfl_xor(c, m);
  }
  __shared__ float ls[16], lc[16];
  const int wid = threadIdx.x >> 6, lane = threadIdx.x & 63;
  if (lane == 0) {
    ls[wid] = s;
    lc[wid] = c;
  }
  __syncthreads();
  if (threadIdx.x == 0) {
    float ts = 0.f, tc = 0.f;
    for (int w = 0; w < 16; ++w) {
      ts += ls[w];
      tc += lc[w];
    }
    out[0] = ts / fmaxf(tc, 1.0f);
  }
}

extern "C" void kernel_launch(void* const* d_in, const int* in_sizes, int n_in,
                              void* d_out, int out_size, void* d_ws,
                              size_t ws_size, hipStream_t stream) {
  const float* E = (const float*)d_in[0];
  const long long* labels = (const long long*)d_in[1];

  float* pos_arr = (float*)d_ws;
  float* all_arr = pos_arr + B_ROWS;
  int* lab32 = (int*)(all_arr + B_ROWS);
  __hip_bfloat16* Ebf = (__hip_bfloat16*)(lab32 + B_ROWS);

  hipMemsetAsync(d_ws, 0, 2 * B_ROWS * sizeof(float), stream);
  prep_kernel<<<B_ROWS / 4, 256, 0, stream>>>(E, labels, Ebf, lab32);
  sim_kernel<<<dim3(B_ROWS / 64, 4), 256, 0, stream>>>(Ebf, lab32, pos_arr,
                                                       all_arr);
  finalize_kernel<<<1, 1024, 0, stream>>>(pos_arr, all_arr, (float*)d_out);
}

// Round 3
// 46.534 us; speedup vs baseline: 1.9577x; 1.9577x over previous
//
#include <hip/hip_runtime.h>
#include <hip/hip_bf16.h>

// InfoNCE loss, B=8192, D=128, T=0.1.
// sim = normalize(E) @ normalize(E)^T / T; per-row masked exp-sums; scalar loss.
// Diagonal terms are INCLUDED in the fused sums and subtracted in finalize via
// a prep-computed diag[i] = exp2(dot_ii) (exact to fp32 sum-order noise).
//
// ws layout:
//   [0    ,  32KB) pos_sum f32[8192]  (zeroed each call)
//   [32KB ,  64KB) all_sum f32[8192]  (zeroed each call)
//   [64KB ,  96KB) lab32   i32[8192]
//   [96KB , 128KB) diag    f32[8192]
//   [128KB, 136KB) lab8p   u8[8192]   (labels, 32-row-group permuted bytes)
//   [136KB, +2MB ) Ebf     bf16[8192*128] (unit rows)

#define B_ROWS 8192
#define D_DIM 128
#define K_SCALE 14.426950408889634f  // log2(e)/0.1
#define JSPLIT 16
#define JCHUNK (B_ROWS / JSPLIT)  // 512
#define TILE_J 64
#define NT (JCHUNK / TILE_J)  // 8

typedef __attribute__((ext_vector_type(8))) short bf16x8;
typedef __attribute__((ext_vector_type(16))) float f32x16;
typedef __attribute__((ext_vector_type(4))) unsigned int u32x4;
typedef unsigned int u32;
typedef unsigned long long u64;

static __device__ __forceinline__ unsigned short bf16_bits(float x) {
  __hip_bfloat16 h = __float2bfloat16(x);
  unsigned short u;
  __builtin_memcpy(&u, &h, 2);
  return u;
}
static __device__ __forceinline__ float f32_from_bits(u32 b) {
  float f;
  __builtin_memcpy(&f, &b, 4);
  return f;
}
static __device__ __forceinline__ float bf16f(unsigned short u) {
  return f32_from_bits((u32)u << 16);
}

// Normalize rows in fp32, emit unit bf16 matrix, int32 labels, permuted label
// bytes, and diag[i] = exp2(<scaled_bf16_row_i, unit_bf16_row_i>), mirroring
// sim_kernel's in-register operand scaling exactly.
__global__ __launch_bounds__(256) void prep_kernel(
    const float* __restrict__ E, const long long* __restrict__ labels,
    __hip_bfloat16* __restrict__ Ebf, int* __restrict__ lab32,
    unsigned char* __restrict__ lab8p, float* __restrict__ diag) {
  const int wid = threadIdx.x >> 6, lane = threadIdx.x & 63;
  const int row = blockIdx.x * 4 + wid;
  const float2 v = *(const float2*)(E + (u64)row * D_DIM + lane * 2);
  float ss = v.x * v.x + v.y * v.y;
#pragma unroll
  for (int m = 1; m < 64; m <<= 1) ss += __shfl_xor(ss, m);
  const float scale = 1.0f / fmaxf(sqrtf(ss), 1e-12f);
  const unsigned short bx = bf16_bits(v.x * scale);
  const unsigned short by = bf16_bits(v.y * scale);
  ((u32*)Ebf)[(u64)row * (D_DIM / 2) + lane] = ((u32)by << 16) | bx;
  // mirror of sim_kernel's scaled-operand rounding
  const float fx = bf16f(bx), fy = bf16f(by);
  const float ax = bf16f(bf16_bits(fx * K_SCALE));
  const float ay = bf16f(bf16_bits(fy * K_SCALE));
  float dot = ax * fx + ay * fy;
#pragma unroll
  for (int m = 1; m < 64; m <<= 1) dot += __shfl_xor(dot, m);
  if (lane == 0) diag[row] = __builtin_amdgcn_exp2f(dot);

  const int gtid = blockIdx.x * 256 + threadIdx.x;
  if (gtid < B_ROWS) {
    const int lab = (int)labels[gtid];
    lab32[gtid] = lab;
    // permute within each 32-row group so the 16 labels an acc-lane needs
    // (rows (r&3)+8*(r>>2)+4*hi) are 16 contiguous bytes per hi-half
    const int local = gtid & 31;
    const int h = (local >> 2) & 1;
    const int r = (local & 3) + 4 * (local >> 3);
    lab8p[(gtid & ~31) + h * 16 + r] = (unsigned char)lab;
  }
}

// Fused sim + exp + masked row sums.
// 256 thr = 4 waves; wave w owns i-rows [bx*128 + w*32, +32) (32x32x16 MFMA,
// swapped operands: D[j][i] = mfma(jfrag_from_lds, ifrag_regs)).
// Output layout: i = lane&31 (per-lane scalar row accumulators!),
// j = (reg&3)+8*(reg>>2)+4*(lane>>5)  [m74/m101].
// grid = (64, JSPLIT); blockIdx.y picks a 512-row j-chunk.
// LDS: 2 x 64x128 bf16 j-tiles (double-buffered), slot-XOR-(row&15) swizzle,
// staged by global_load_lds dwordx4 with pre-swizzled global source (m173).
__global__ __launch_bounds__(256) void sim_kernel(
    const __hip_bfloat16* __restrict__ Ebf, const int* __restrict__ lab32,
    const unsigned char* __restrict__ lab8p, float* __restrict__ pos_arr,
    float* __restrict__ all_arr) {
  __shared__ __align__(16) unsigned char lds[2][TILE_J * 256];

  const int t = threadIdx.x;
  const int wid = t >> 6, lane = t & 63;
  const int l31 = lane & 31, hi = lane >> 5;
  const int i0w = blockIdx.x * 128 + wid * 32;
  const int jbase0 = blockIdx.y * JCHUNK;

  // register-resident i-side fragments (MFMA B operand), scaled by K_SCALE
  bf16x8 ifrag[8];
  {
    const __hip_bfloat16* src = Ebf + (u64)(i0w + l31) * D_DIM + hi * 8;
#pragma unroll
    for (int ks = 0; ks < 8; ++ks) {
      bf16x8 raw = *(const bf16x8*)(src + ks * 16);
      bf16x8 s;
#pragma unroll
      for (int e = 0; e < 8; ++e)
        s[e] = (short)bf16_bits(bf16f((unsigned short)raw[e]) * K_SCALE);
      ifrag[ks] = s;
    }
  }
  const int labi = lab32[i0w + l31];

  // swizzled LDS read addresses: row=l31, slot=ks*2+hi, slot'=slot^(row&15);
  // valid for both jsubs since (jsub*32 + l31)&15 == lane&15
  u32 raddr[8];
#pragma unroll
  for (int ks = 0; ks < 8; ++ks)
    raddr[ks] = (u32)(l31 * 256) + (u32)((((ks * 2 + hi) ^ (lane & 15))) << 4);

  // staging source pointers: wave w call i stages LDS rows w*16+i*4+(l>>4)
  // linearly; global slot pre-swizzled: slot_g = (l&15) ^ (i*4 + (l>>4))
  const unsigned char* gsrc[4];
  {
    const unsigned char* gb = (const unsigned char*)Ebf;
    const int l4 = lane >> 4, sl = lane & 15;
#pragma unroll
    for (int i = 0; i < 4; ++i) {
      const int rloc = wid * 16 + i * 4 + l4;
      gsrc[i] = gb + (u64)(jbase0 + rloc) * 256 + (u64)((sl ^ (i * 4 + l4)) * 16);
    }
  }

  auto stage = [&](int buf) {
#pragma unroll
    for (int i = 0; i < 4; ++i) {
      __builtin_amdgcn_global_load_lds(
          (const __attribute__((address_space(1))) u32*)(gsrc[i]),
          (__attribute__((address_space(3)))
               u32*)(&lds[buf][wid * 4096 + i * 1024]),
          16, 0, 0);
      gsrc[i] += TILE_J * 256;
    }
  };

  float pos0 = 0.f, pos1 = 0.f, all0 = 0.f, all1 = 0.f;

  stage(0);
  __syncthreads();

  for (int tile = 0; tile < NT; ++tile) {
    const int cur = tile & 1;
    if (tile + 1 < NT) stage(cur ^ 1);  // prefetch next into other buffer
    const int jbase = jbase0 + tile * TILE_J;
    const unsigned char* lbuf = lds[cur];
#pragma unroll
    for (int jsub = 0; jsub < 2; ++jsub) {
      f32x16 acc = {};
#pragma unroll
      for (int ks = 0; ks < 8; ++ks) {
        bf16x8 jfrag = *(const bf16x8*)(lbuf + raddr[ks] + jsub * 8192);
        acc = __builtin_amdgcn_mfma_f32_32x32x16_bf16(jfrag, ifrag[ks], acc, 0,
                                                      0, 0);
      }
      // 16 j-labels for this lane, one broadcast 16B load (prep-permuted)
      const u32x4 labv =
          *(const u32x4*)(lab8p + jbase + jsub * 32 + hi * 16);
#pragma unroll
      for (int r = 0; r < 16; ++r) {
        const float p = __builtin_amdgcn_exp2f(acc[r]);
        const int labj = (int)((labv[r >> 2] >> ((r & 3) * 8)) & 0xff);
        if (r & 1) {
          all1 += p;
          pos1 += (labj == labi) ? p : 0.f;
        } else {
          all0 += p;
          pos0 += (labj == labi) ? p : 0.f;
        }
      }
    }
    __syncthreads();
  }

  float pa = pos0 + pos1, aa = all0 + all1;
  pa += __shfl_xor(pa, 32);  // lane & lane+32 hold same i, disjoint j-halves
  aa += __shfl_xor(aa, 32);
  if (hi == 0) {
    atomicAdd(&pos_arr[i0w + l31], pa);
    atomicAdd(&all_arr[i0w + l31], aa);
  }
}

__global__ __launch_bounds__(1024) void finalize_kernel(
    const float* __restrict__ pos_arr, const float* __restrict__ all_arr,
    const float* __restrict__ diag, float* __restrict__ out) {
  float s = 0.f, c = 0.f;
  for (int r = threadIdx.x; r < B_ROWS; r += 1024) {
    const float d = diag[r];
    const float ps = pos_arr[r] - d;   // remove diagonal term
    const float as_ = all_arr[r] - d;
    if (ps > 0.f) {
      s += logf(as_) - logf(ps);
      c += 1.f;
    }
  }
#pragma unroll
  for (int m = 1; m < 64; m <<= 1) {
    s += __shfl_xor(s, m);
    c += __shfl_xor(c, m);
  }
  __shared__ float ls[16], lc[16];
  const int wid = threadIdx.x >> 6, lane = threadIdx.x & 63;
  if (lane == 0) {
    ls[wid] = s;
    lc[wid] = c;
  }
  __syncthreads();
  if (threadIdx.x == 0) {
    float ts = 0.f, tc = 0.f;
    for (int w = 0; w < 16; ++w) {
      ts += ls[w];
      tc += lc[w];
    }
    out[0] = ts / fmaxf(tc, 1.0f);
  }
}

extern "C" void kernel_launch(void* const* d_in, const int* in_sizes, int n_in,
                              void* d_out, int out_size, void* d_ws,
                              size_t ws_size, hipStream_t stream) {
  const float* E = (const float*)d_in[0];
  const long long* labels = (const long long*)d_in[1];

  float* pos_arr = (float*)d_ws;
  float* all_arr = pos_arr + B_ROWS;
  int* lab32 = (int*)(all_arr + B_ROWS);
  float* diag = (float*)(lab32 + B_ROWS);
  unsigned char* lab8p = (unsigned char*)(diag + B_ROWS);
  __hip_bfloat16* Ebf = (__hip_bfloat16*)(lab8p + B_ROWS);

  hipMemsetAsync(d_ws, 0, 2 * B_ROWS * sizeof(float), stream);
  prep_kernel<<<B_ROWS / 4, 256, 0, stream>>>(E, labels, Ebf, lab32, lab8p,
                                              diag);
  sim_kernel<<<dim3(B_ROWS / 128, JSPLIT), 256, 0, stream>>>(
      Ebf, lab32, lab8p, pos_arr, all_arr);
  finalize_kernel<<<1, 1024, 0, stream>>>(pos_arr, all_arr, diag,
                                          (float*)d_out);
}